// Round 1
// baseline (16.098 us; speedup 1.0000x reference)
//
#include <hip/hip_runtime.h>

// RecurrentLTI: A_dsc is 256 identical 2x2 blocks a*I + w*J (J=[[0,1],[-1,0]]).
// Block state (x1,x2) as complex s = x1 + i*x2 evolves s' = lam*s + beta_i*u,
// lam = a - i*w (identical for all blocks). By linearity s_i = beta_i * S with
// S_{k+1} = lam*S_k + u_k, S_0 = 0.
// y_k = c@x_{k+1} + d*u_k = Re(Gamma * S_{k+1}) + d*u_k,
// Gamma = sum_i (c[2i] - i c[2i+1]) * (b[2i] + i b[2i+1]).
// => single complex first-order scan over L=65536, done as a 3-kernel
// chunked parallel scan (1024 chunks of 64, wave-level Kogge-Stone).

struct C2 { float r, i; };

__device__ __forceinline__ C2 cmul(C2 a, C2 b) {
    return C2{ a.r * b.r - a.i * b.i, a.r * b.i + a.i * b.r };
}

// acc + p * x
__device__ __forceinline__ C2 cfma(C2 p, C2 x, C2 acc) {
    C2 o;
    o.r = fmaf(p.r, x.r, fmaf(-p.i, x.i, acc.r));
    o.i = fmaf(p.r, x.i, fmaf( p.i, x.r, acc.i));
    return o;
}

__device__ __forceinline__ C2 load_lambda(const float* __restrict__ A) {
    // A row-major [512][512]; block 0: A[0][0]=a, A[0][1]=w; lam = a - i*w
    return C2{ A[0], -A[1] };
}

// ---------------- Kernel A: per-64-chunk aggregates ----------------
__global__ __launch_bounds__(256) void kernA(const float* __restrict__ u,
                                             const float* __restrict__ A,
                                             float2* __restrict__ agg) {
    const int lane = threadIdx.x & 63;
    const int gw   = (blockIdx.x * 256 + threadIdx.x) >> 6;   // 0..1023

    C2 lam = load_lambda(A);
    C2 pw[6];
    pw[0] = lam;
#pragma unroll
    for (int s = 1; s < 6; ++s) pw[s] = cmul(pw[s - 1], pw[s - 1]);

    C2 v{ u[gw * 64 + lane], 0.0f };
#pragma unroll
    for (int s = 0; s < 6; ++s) {
        const int d = 1 << s;
        float ur = __shfl_up(v.r, d, 64);
        float ui = __shfl_up(v.i, d, 64);
        if (lane >= d) v = cfma(pw[s], C2{ ur, ui }, v);
    }
    if (lane == 63) agg[gw] = make_float2(v.r, v.i);
}

// ------- Kernel B: scan 1024 aggregates -> exclusive starts; Gamma -------
__global__ __launch_bounds__(1024) void kernB(const float* __restrict__ A,
                                              const float* __restrict__ b,
                                              const float* __restrict__ c,
                                              const float2* __restrict__ agg,
                                              float2* __restrict__ start,
                                              float2* __restrict__ gam) {
    __shared__ float2 sh[1024];
    __shared__ float2 wred[16];

    const int t    = threadIdx.x;
    const int lane = t & 63;
    const int w    = t >> 6;

    C2 lam = load_lambda(A);
    C2 l64 = lam;
#pragma unroll
    for (int s = 0; s < 6; ++s) l64 = cmul(l64, l64);       // lam^64
    // pw64[j] = lam^(64 * 2^j), j = 0..9  (up to lam^32768)
    C2 pw64[10];
    pw64[0] = l64;
#pragma unroll
    for (int j = 1; j < 10; ++j) pw64[j] = cmul(pw64[j - 1], pw64[j - 1]);

    float2 av = agg[t];
    C2 v{ av.x, av.y };
    // wave-level scan over 64 chunk aggregates (element multiplier lam^64)
#pragma unroll
    for (int s = 0; s < 6; ++s) {
        const int d = 1 << s;
        float ur = __shfl_up(v.r, d, 64);
        float ui = __shfl_up(v.i, d, 64);
        if (lane >= d) v = cfma(pw64[s], C2{ ur, ui }, v);
    }
    if (lane == 63) wred[w] = make_float2(v.r, v.i);
    __syncthreads();

    // cross-wave scan of 16 wave totals (element multiplier lam^4096)
    if (t < 16) {
        C2 x{ wred[t].x, wred[t].y };
#pragma unroll
        for (int s = 0; s < 4; ++s) {
            const int d = 1 << s;
            float ur = __shfl_up(x.r, d, 64);
            float ui = __shfl_up(x.i, d, 64);
            if (t >= d) x = cfma(pw64[6 + s], C2{ ur, ui }, x);
        }
        wred[t] = make_float2(x.r, x.i);
    }
    __syncthreads();

    // combine: inclusive over chunks 0..t
    C2 full = v;
    if (w > 0) {
        C2 p{ 1.0f, 0.0f };
        const int e = lane + 1;                 // need (lam^64)^(lane+1)
#pragma unroll
        for (int j = 0; j < 7; ++j)
            if ((e >> j) & 1) p = cmul(p, pw64[j]);
        float2 pr = wred[w - 1];
        full = cfma(p, C2{ pr.x, pr.y }, full);
    }
    sh[t] = make_float2(full.r, full.i);
    __syncthreads();

    // exclusive start state for chunk t = inclusive of chunk t-1
    start[t] = (t == 0) ? make_float2(0.0f, 0.0f) : sh[t - 1];

    // ---- Gamma = sum_i (c1 - i c2)(b1 + i b2) over 256 blocks ----
    C2 g{ 0.0f, 0.0f };
    if (t < 256) {
        const float b1 = b[2 * t], b2 = b[2 * t + 1];
        const float c1 = c[2 * t], c2 = c[2 * t + 1];
        g.r = fmaf(b1, c1, b2 * c2);
        g.i = fmaf(c1, b2, -(c2 * b1));
    }
#pragma unroll
    for (int d = 32; d > 0; d >>= 1) {
        g.r += __shfl_xor(g.r, d, 64);
        g.i += __shfl_xor(g.i, d, 64);
    }
    __syncthreads();   // all combines done reading wred before reuse
    if (lane == 0) wred[w] = make_float2(g.r, g.i);
    __syncthreads();
    if (t == 0) {
        float gr = 0.0f, gi = 0.0f;
#pragma unroll
        for (int k = 0; k < 16; ++k) { gr += wred[k].x; gi += wred[k].y; }
        gam[0] = make_float2(gr, gi);
    }
}

// ---------------- Kernel C: rescan chunks with carry, write y ----------------
__global__ __launch_bounds__(256) void kernC(const float* __restrict__ u,
                                             const float* __restrict__ A,
                                             const float* __restrict__ dsc,
                                             const float2* __restrict__ start,
                                             const float2* __restrict__ gam,
                                             float* __restrict__ y) {
    const int lane = threadIdx.x & 63;
    const int gw   = (blockIdx.x * 256 + threadIdx.x) >> 6;

    C2 lam = load_lambda(A);
    C2 pw[6];
    pw[0] = lam;
#pragma unroll
    for (int s = 1; s < 6; ++s) pw[s] = cmul(pw[s - 1], pw[s - 1]);

    const float uk = u[gw * 64 + lane];
    C2 v{ uk, 0.0f };
    if (lane == 0) {
        // fold chunk-start state into lane 0: v0 = u0 + lam * S_start
        float2 st = start[gw];
        v = cfma(lam, C2{ st.x, st.y }, v);
    }
#pragma unroll
    for (int s = 0; s < 6; ++s) {
        const int d = 1 << s;
        float ur = __shfl_up(v.r, d, 64);
        float ui = __shfl_up(v.i, d, 64);
        if (lane >= d) v = cfma(pw[s], C2{ ur, ui }, v);
    }

    const float2 G  = gam[0];
    const float  dv = dsc[0];
    // y = Gr*Re(S) - Gi*Im(S) + d*u
    y[gw * 64 + lane] = fmaf(G.x, v.r, fmaf(-G.y, v.i, dv * uk));
}

extern "C" void kernel_launch(void* const* d_in, const int* in_sizes, int n_in,
                              void* d_out, int out_size, void* d_ws, size_t ws_size,
                              hipStream_t stream) {
    const float* u = (const float*)d_in[0];   // [65536]
    const float* A = (const float*)d_in[1];   // [512*512]
    const float* b = (const float*)d_in[2];   // [512]
    const float* c = (const float*)d_in[3];   // [512]
    const float* d = (const float*)d_in[4];   // [1]
    float* y = (float*)d_out;                 // [65536]

    float2* agg   = (float2*)d_ws;            // 1024 chunk aggregates
    float2* start = agg + 1024;               // 1024 exclusive chunk starts
    float2* gam   = start + 1024;             // Gamma

    kernA<<<256, 256, 0, stream>>>(u, A, agg);
    kernB<<<1, 1024, 0, stream>>>(A, b, c, agg, start, gam);
    kernC<<<256, 256, 0, stream>>>(u, A, d, start, gam, y);
}